// Round 3
// baseline (347.166 us; speedup 1.0000x reference)
//
#include <hip/hip_runtime.h>
#include <stdint.h>

#define DI static __device__ __forceinline__

constexpr int NTOK = 9216;   // 96*96 feat tokens per batch
constexpr float ATT_SCALE = 0.125f;

typedef short bf16x8 __attribute__((ext_vector_type(8)));
typedef float f32x4  __attribute__((ext_vector_type(4)));

DI f32x4 mfma16(bf16x8 a, bf16x8 b, f32x4 c) {
  return __builtin_amdgcn_mfma_f32_16x16x32_bf16(a, b, c, 0, 0, 0);
}

DI float lo2f(uint32_t u) { union { uint32_t i; float f; } v; v.i = u << 16; return v.f; }
DI float hi2f(uint32_t u) { union { uint32_t i; float f; } v; v.i = u & 0xffff0000u; return v.f; }
DI float b2f(uint16_t u) { union { uint32_t i; float f; } v; v.i = ((uint32_t)u) << 16; return v.f; }
DI uint16_t f2b(float f) {
  union { float f; uint32_t i; } v; v.f = f;
  uint32_t r = (v.i + 0x7fffu + ((v.i >> 16) & 1u)) >> 16;
  return (uint16_t)r;
}

// ---- dtype-generic element access (DT: 1 = bf16 storage, 0 = fp32 storage) --
template<int DT> DI float ld1(const void* p, size_t off) {
  if constexpr (DT) return b2f(((const uint16_t*)p)[off]);
  else              return ((const float*)p)[off];
}
template<int DT> DI void st1(void* p, size_t off, float v) {
  if constexpr (DT) ((uint16_t*)p)[off] = f2b(v);
  else              ((float*)p)[off] = v;
}

// ---------------------------------------------------------------------------
// dtype detector (wave-parallel): flag=1 -> bf16 inputs, 0 -> fp32 inputs
// ---------------------------------------------------------------------------
__global__ void detect_dtype(const uint32_t* __restrict__ w, int* __restrict__ flag) {
  const int l = threadIdx.x;   // 64 lanes
  int cl = 0;
  #pragma unroll
  for (int i = 0; i < 4; ++i) {
    const float b = b2f((uint16_t)(w[l + i * 64] & 0xffffu));
    const float ab = fabsf(b);
    cl += (ab > 1e-4f && ab < 0.5f) ? 1 : 0;
  }
  cl += __shfl_xor(cl, 1);  cl += __shfl_xor(cl, 2);  cl += __shfl_xor(cl, 4);
  cl += __shfl_xor(cl, 8);  cl += __shfl_xor(cl, 16); cl += __shfl_xor(cl, 32);
  if (l == 0) flag[0] = (cl >= 128) ? 1 : 0;
}

// ---------------------------------------------------------------------------
// Weight prep (bf16, MFMA-ready), natural k-order.
// ---------------------------------------------------------------------------
template<int DT>
DI void prep_w_body(const void* __restrict__ Wfqv, const void* __restrict__ Wfo,
                    uint16_t* __restrict__ WqvP, uint16_t* __restrict__ WfoP)
{
  const int r = blockIdx.x, c = threadIdx.x;
  if (r < 512) {
    const int sel = r >> 8, within = r & 255;
    const int h = within >> 6, d = within & 63;
    const int src = sel * 256 + d * 4 + h;
    WqvP[(size_t)r * 256 + c] = f2b(ld1<DT>(Wfqv, (size_t)src * 256 + c));
  } else {
    const int ro = r - 512;
    WfoP[(size_t)ro * 256 + c] =
        f2b(ld1<DT>(Wfo, (size_t)ro * 256 + (c & 63) * 4 + (c >> 6)));
  }
}
__global__ __launch_bounds__(256) void prep_w(
    const void* Wfqv, const void* Wfo, uint16_t* WqvP, uint16_t* WfoP,
    const int* __restrict__ flag)
{
  if (flag[0]) prep_w_body<1>(Wfqv, Wfo, WqvP, WfoP);
  else         prep_w_body<0>(Wfqv, Wfo, WqvP, WfoP);
}

// ---------------------------------------------------------------------------
// GEMM0 (QV projection), MFMA. Grid (144 n-slabs, 4 batch), 256 thr.
// One block = 64 tokens x ALL 512 output channels (wave w = head w): feat
// fetched exactly once. X tile staged transposed once, barrier-free k-loop.
// ---------------------------------------------------------------------------
constexpr int P0 = 280;   // gemm0 LDS token-row pitch (elems)

template<int DT>
DI void gemm0_body(uint16_t* Xs, const uint16_t* __restrict__ WqvP,
                   const void* __restrict__ X,
                   uint16_t* __restrict__ FQ, uint16_t* __restrict__ FVt)
{
  const int tid = threadIdx.x;
  const int w = tid >> 6, lane = tid & 63;
  const int l = lane & 15, quad = lane >> 4;
  const int n0 = blockIdx.x * 64;
  const int bb = blockIdx.y;
  const size_t bh = (size_t)bb * 4 + w;    // wave w handles head w

  // ---- stage X[256k][64n] -> Xs[n][k] bf16, one shot
  {
    const int nh = (tid & 1) * 32;
    #pragma unroll
    for (int p = 0; p < 2; ++p) {
      const int c = p * 128 + (tid >> 1);
      const size_t g = ((size_t)bb * 256 + c) * NTOK + n0 + nh;
      if constexpr (DT) {
        #pragma unroll
        for (int u = 0; u < 4; ++u) {
          const uint4 v = *(const uint4*)((const uint16_t*)X + g + u * 8);
          const uint16_t* pk = (const uint16_t*)&v;
          #pragma unroll
          for (int j = 0; j < 8; ++j)
            Xs[(size_t)(nh + u * 8 + j) * P0 + c] = pk[j];
        }
      } else {
        #pragma unroll
        for (int u = 0; u < 8; ++u) {
          const float4 v = *(const float4*)((const float*)X + g + u * 4);
          Xs[(size_t)(nh + u * 4 + 0) * P0 + c] = f2b(v.x);
          Xs[(size_t)(nh + u * 4 + 1) * P0 + c] = f2b(v.y);
          Xs[(size_t)(nh + u * 4 + 2) * P0 + c] = f2b(v.z);
          Xs[(size_t)(nh + u * 4 + 3) * P0 + c] = f2b(v.w);
        }
      }
    }
  }
  __syncthreads();

  f32x4 acc[8][4];
  #pragma unroll
  for (int a = 0; a < 8; ++a)
    #pragma unroll
    for (int b = 0; b < 4; ++b) { acc[a][b].x = 0.f; acc[a][b].y = 0.f; acc[a][b].z = 0.f; acc[a][b].w = 0.f; }

  for (int ks = 0; ks < 8; ++ks) {
    bf16x8 af[8];
    #pragma unroll
    for (int mt = 0; mt < 8; ++mt) {
      const int arow = (mt >> 2) * 256 + w * 64 + (mt & 3) * 16 + l;
      af[mt] = *(const bf16x8*)(WqvP + (size_t)arow * 256 + ks * 32 + quad * 8);
    }
    #pragma unroll
    for (int nt = 0; nt < 4; ++nt) {
      const bf16x8 bv = *(const bf16x8*)(Xs + (size_t)(nt * 16 + l) * P0 + ks * 32 + quad * 8);
      #pragma unroll
      for (int mt = 0; mt < 8; ++mt)
        acc[mt][nt] = mfma16(af[mt], bv, acc[mt][nt]);
    }
  }
  #pragma unroll
  for (int mt = 0; mt < 8; ++mt)
    #pragma unroll
    for (int nt = 0; nt < 4; ++nt) {
      const int n = n0 + nt * 16 + l;
      if (mt < 4) {
        union { uint16_t h[4]; uint2 u; } pk;
        #pragma unroll
        for (int r = 0; r < 4; ++r) pk.h[r] = f2b(acc[mt][nt][r]);
        *(uint2*)(FQ + (bh * NTOK + n) * 64 + mt * 16 + quad * 4) = pk.u;
      } else {
        const int itile = n >> 5, io = n & 31;
        #pragma unroll
        for (int r = 0; r < 4; ++r)
          FVt[(((size_t)bh * 288 + itile) * 64 + (mt - 4) * 16 + quad * 4 + r) * 32 + io] =
              f2b(acc[mt][nt][r]);
      }
    }
}
__global__ __launch_bounds__(256) void gemm0_mfma(
    const uint16_t* WqvP, const void* X, uint16_t* FQ, uint16_t* FVt,
    const int* __restrict__ flag)
{
  __shared__ __align__(16) uint16_t Xs[64 * P0];
  if (flag[0]) gemm0_body<1>(Xs, WqvP, X, FQ, FVt);
  else         gemm0_body<0>(Xs, WqvP, X, FQ, FVt);
}

// ---------------------------------------------------------------------------
// GEMM1 (feat out projection), MFMA, LDS-free. Grid (36, 4 o-slabs, 4 b).
// ---------------------------------------------------------------------------
template<int DT>
DI void gemm1_body(const uint16_t* __restrict__ WfoP, const uint16_t* __restrict__ FO,
                   void* __restrict__ out)
{
  const int tid = threadIdx.x;
  const int w = tid >> 6, lane = tid & 63;
  const int l = lane & 15, quad = lane >> 4;
  const int n0 = blockIdx.x * 256;
  const int o0 = blockIdx.y * 64;
  const int bb = blockIdx.z;

  f32x4 acc[4][4];
  #pragma unroll
  for (int a = 0; a < 4; ++a)
    #pragma unroll
    for (int b = 0; b < 4; ++b) { acc[a][b].x = 0.f; acc[a][b].y = 0.f; acc[a][b].z = 0.f; acc[a][b].w = 0.f; }

  for (int ks = 0; ks < 8; ++ks) {
    const int h2 = ks >> 1;
    const int doff = (ks & 1) * 32 + quad * 8;
    bf16x8 af[4];
    #pragma unroll
    for (int mt = 0; mt < 4; ++mt)
      af[mt] = *(const bf16x8*)(WfoP + (size_t)(o0 + mt * 16 + l) * 256 + ks * 32 + quad * 8);
    #pragma unroll
    for (int nt = 0; nt < 4; ++nt) {
      const int n = n0 + w * 64 + nt * 16 + l;
      const bf16x8 bv = *(const bf16x8*)(FO + ((size_t)(bb * 4 + h2) * NTOK + n) * 64 + doff);
      #pragma unroll
      for (int mt = 0; mt < 4; ++mt)
        acc[mt][nt] = mfma16(af[mt], bv, acc[mt][nt]);
    }
  }
  #pragma unroll
  for (int mt = 0; mt < 4; ++mt)
    #pragma unroll
    for (int nt = 0; nt < 4; ++nt) {
      const int n = n0 + w * 64 + nt * 16 + l;
      #pragma unroll
      for (int r = 0; r < 4; ++r)
        st1<DT>(out, ((size_t)bb * 256 + o0 + mt * 16 + quad * 4 + r) * NTOK + n,
                acc[mt][nt][r]);
    }
}
__global__ __launch_bounds__(256) void gemm1_mfma(
    const uint16_t* WfoP, const uint16_t* FO, void* out,
    const int* __restrict__ flag)
{
  if (flag[0]) gemm1_body<1>(WfoP, FO, out);
  else         gemm1_body<0>(WfoP, FO, out);
}

// ---------------------------------------------------------------------------
// map QV projection (tiny): MQ[bh][m][d] token-major, MVT[bh][d][m] d-major
// ---------------------------------------------------------------------------
template<int DT>
DI void map_qv_body(const void* __restrict__ Wqv, const void* __restrict__ smap,
                    uint16_t* __restrict__ MQ, uint16_t* __restrict__ MVT)
{
  const int o = blockIdx.x, bb = blockIdx.y, m = threadIdx.x;
  float acc = 0.f;
  #pragma unroll 8
  for (int c = 0; c < 256; ++c)
    acc += ld1<DT>(Wqv, (size_t)o * 256 + c) *
           ld1<DT>(smap, (size_t)bb * 65536 + (size_t)c * 256 + m);
  const int oc = o & 255;
  const int h = oc & 3, d = oc >> 2;
  if (o < 256) MQ[(((size_t)bb * 4 + h) * 256 + m) * 64 + d] = f2b(acc);
  else         MVT[(((size_t)bb * 4 + h) * 64 + d) * 256 + m] = f2b(acc);
}
__global__ __launch_bounds__(256) void map_qv(
    const void* Wqv, const void* smap, uint16_t* MQ, uint16_t* MVT,
    const int* __restrict__ flag)
{
  if (flag[0]) map_qv_body<1>(Wqv, smap, MQ, MVT);
  else         map_qv_body<0>(Wqv, smap, MQ, MVT);
}

// ---------------------------------------------------------------------------
// Fused bidirectional attention, MFMA 16x16x32 bf16. Grid (36, 16).
// Round-3 restructure:
//  - ETsh ELIMINATED: the column phase consumed only intra-wave data (each
//    wave reads its own j-rows that it just computed). Replaced by 8
//    __shfl per fragment: receiver (l,q) pulls pk words from lanes
//    l+32*(q&1) and +16, selecting mt by q>>1. Verified: src quad
//    (q&1)*2+(k>>2) holds rows (q>>1)*16+(q&1)*8+r at col l.
//  - Column phase moved BEFORE barrier1 (no cross-wave dependency), so the
//    barrier-bracketed path is just the row phase.
//  - LDS 43.5 -> 23.0 KB; __launch_bounds__(256,4) targets 64 VGPR + 64
//    AGPR = 128 regs -> 4 blocks/CU (16 waves, was 12). kb/avr loaded
//    in-loop (L2-resident; compiler couldn't hold the hoist anyway).
// ---------------------------------------------------------------------------
constexpr int PJ = 280;  // E[i][j] row pitch (560B rows, 16B-aligned)
constexpr int PO = 72;   // Osh row pitch (144 B: 16B-aligned, bank-spread)
constexpr int NGRP = 36; // partial groups (= blocks) per bh

__global__ __launch_bounds__(256, 4) void attn_mfma(
    const uint16_t* __restrict__ FQ, const uint16_t* __restrict__ FVt,
    const uint16_t* __restrict__ MQ, const uint16_t* __restrict__ MVT,
    uint16_t* __restrict__ FO, uint16_t* __restrict__ P)
{
  __shared__ __align__(16) uint16_t Esh[32 * PJ];    // [i][j]  17,920 B
  __shared__ __align__(16) uint16_t Osh[32 * PO];    // [i][d]   4,608 B
  __shared__ float RS[4][32];                        //            512 B
  const int tid = threadIdx.x;
  const int w = tid >> 6;
  const int lane = tid & 63;
  const int l = lane & 15, quad = lane >> 4;
  const int blk = blockIdx.x, bh = blockIdx.y;
  const uint16_t* FQh  = FQ  + (size_t)bh * NTOK * 64;
  const uint16_t* FVth = FVt + (size_t)bh * 288 * 64 * 32;
  const uint16_t* MQh  = MQ  + (size_t)bh * 256 * 64;
  const uint16_t* MVTh = MVT + (size_t)bh * 64 * 256;
  uint16_t* FOh = FO + (size_t)bh * NTOK * 64;

  f32x4 numacc[4][4];
  #pragma unroll
  for (int a = 0; a < 4; ++a)
    #pragma unroll
    for (int b = 0; b < 4; ++b) { numacc[a][b].x = 0.f; numacc[a][b].y = 0.f; numacc[a][b].z = 0.f; numacc[a][b].w = 0.f; }
  float csum[4] = {0.f, 0.f, 0.f, 0.f};

  const int srcA = l + ((quad & 1) << 5);   // shuffle source lanes (col phase)
  const int srcB = srcA + 16;

  for (int t = 0; t < 8; ++t) {
    const int it = blk * 8 + t;
    const int i0 = it * 32;

    // ---- QK phase: e_ij into Esh [i][j] + pku regs (col-phase source)
    bf16x8 qa[2][2];
    #pragma unroll
    for (int mt = 0; mt < 2; ++mt)
      #pragma unroll
      for (int kbi = 0; kbi < 2; ++kbi)
        qa[mt][kbi] = *(const bf16x8*)(FQh + (size_t)(i0 + mt * 16 + l) * 64 + kbi * 32 + quad * 8);

    uint2 pku[4][2];
    float rsum[2][4] = {{0.f,0.f,0.f,0.f},{0.f,0.f,0.f,0.f}};
    #pragma unroll
    for (int jt = 0; jt < 4; ++jt) {
      const int j0 = w * 64 + jt * 16;
      const bf16x8 kb0 = *(const bf16x8*)(MQh + (size_t)(j0 + l) * 64 + quad * 8);
      const bf16x8 kb1 = *(const bf16x8*)(MQh + (size_t)(j0 + l) * 64 + 32 + quad * 8);
      #pragma unroll
      for (int mt = 0; mt < 2; ++mt) {
        f32x4 acc = {0.f, 0.f, 0.f, 0.f};
        acc = mfma16(qa[mt][0], kb0, acc);
        acc = mfma16(qa[mt][1], kb1, acc);
        union { uint16_t h[4]; uint2 u; } pk;
        #pragma unroll
        for (int r = 0; r < 4; ++r) {
          const float e = __expf(acc[r] * ATT_SCALE);
          rsum[mt][r] += e;
          csum[jt] += e;
          pk.h[r] = f2b(e);
          Esh[(mt * 16 + quad * 4 + r) * PJ + j0 + l] = pk.h[r];
        }
        pku[jt][mt] = pk.u;
      }
    }

    // ---- issue this iter's FVt loads (consumed in col phase below)
    bf16x8 av[4];
    #pragma unroll
    for (int mt = 0; mt < 4; ++mt)
      av[mt] = *(const bf16x8*)(FVth + ((size_t)it * 64 + mt * 16 + l) * 32 + quad * 8);

    // ---- row-sum reduce -> RS (for row-phase normalization)
    #pragma unroll
    for (int mt = 0; mt < 2; ++mt)
      #pragma unroll
      for (int r = 0; r < 4; ++r) {
        float v = rsum[mt][r];
        v += __shfl_xor(v, 1); v += __shfl_xor(v, 2);
        v += __shfl_xor(v, 4); v += __shfl_xor(v, 8);
        if (l == 0) RS[w][mt * 16 + quad * 4 + r] = v;
      }

    // ---- column phase (pre-barrier, intra-wave): NUM^T[d][j] += V^T x E
    #pragma unroll
    for (int nt2 = 0; nt2 < 4; ++nt2) {
      const int a0 = __shfl((int)pku[nt2][0].x, srcA);
      const int a1 = __shfl((int)pku[nt2][0].y, srcA);
      const int a2 = __shfl((int)pku[nt2][0].x, srcB);
      const int a3 = __shfl((int)pku[nt2][0].y, srcB);
      const int b0 = __shfl((int)pku[nt2][1].x, srcA);
      const int b1 = __shfl((int)pku[nt2][1].y, srcA);
      const int b2 = __shfl((int)pku[nt2][1].x, srcB);
      const int b3 = __shfl((int)pku[nt2][1].y, srcB);
      const bool hi = (quad >> 1) != 0;
      union { int i[4]; bf16x8 v; } bu;
      bu.i[0] = hi ? b0 : a0;
      bu.i[1] = hi ? b1 : a1;
      bu.i[2] = hi ? b2 : a2;
      bu.i[3] = hi ? b3 : a3;
      #pragma unroll
      for (int mt = 0; mt < 4; ++mt)
        numacc[mt][nt2] = mfma16(av[mt], bu.v, numacc[mt][nt2]);
    }
    __syncthreads();

    // ---- row phase: feat_o^T[d][i] = MVT x E^T, normalized -> Osh
    {
      float rinv[2];
      #pragma unroll
      for (int nt = 0; nt < 2; ++nt) {
        const int i_ = nt * 16 + l;
        rinv[nt] = 1.f / (RS[0][i_] + RS[1][i_] + RS[2][i_] + RS[3][i_]);
      }
      f32x4 oacc[2];
      oacc[0].x=0.f;oacc[0].y=0.f;oacc[0].z=0.f;oacc[0].w=0.f;
      oacc[1]=oacc[0];
      #pragma unroll
      for (int ks = 0; ks < 8; ++ks) {
        const bf16x8 avr = *(const bf16x8*)(MVTh + (size_t)(w * 16 + l) * 256 + ks * 32 + quad * 8);
        #pragma unroll
        for (int nt = 0; nt < 2; ++nt) {
          const bf16x8 bv = *(const bf16x8*)(Esh + (size_t)(nt * 16 + l) * PJ + ks * 32 + quad * 8);
          oacc[nt] = mfma16(avr, bv, oacc[nt]);
        }
      }
      #pragma unroll
      for (int nt = 0; nt < 2; ++nt) {
        union { uint16_t h[4]; uint2 u; } pk;
        #pragma unroll
        for (int r = 0; r < 4; ++r) pk.h[r] = f2b(oacc[nt][r] * rinv[nt]);
        *(uint2*)(Osh + (nt * 16 + l) * PO + w * 16 + quad * 4) = pk.u;
      }
    }
    __syncthreads();

    // ---- FO write: full 128-B line per token (8 thr x uint4)
    {
      const int ti = tid >> 3, c = tid & 7;
      *(uint4*)(FOh + (size_t)(i0 + ti) * 64 + c * 8) =
          *(const uint4*)(Osh + ti * PO + c * 8);
    }
  }

  // ---- flush partials (plain bf16 stores, no atomics)
  uint16_t* Pb = P + ((size_t)bh * NGRP + blk) * 65 * 256;
  #pragma unroll
  for (int mt = 0; mt < 4; ++mt)
    #pragma unroll
    for (int nt2 = 0; nt2 < 4; ++nt2)
      #pragma unroll
      for (int r = 0; r < 4; ++r)
        Pb[(mt * 16 + quad * 4 + r) * 256 + w * 64 + nt2 * 16 + l] =
            f2b(numacc[mt][nt2][r]);
  #pragma unroll
  for (int jt = 0; jt < 4; ++jt) {
    float v = csum[jt];
    v += __shfl_xor(v, 16); v += __shfl_xor(v, 32);
    if (quad == 0) Pb[64 * 256 + w * 64 + jt * 16 + l] = f2b(v);
  }
}

// ---------------------------------------------------------------------------
// reduce partials -> map_o: MO[b][c=d*4+h][j] = sum_g NUM / sum_g CS
// ---------------------------------------------------------------------------
__global__ __launch_bounds__(256) void reduce_map(
    const uint16_t* __restrict__ P, uint16_t* __restrict__ MO)
{
  const int idx = blockIdx.x * 256 + threadIdx.x;   // 262144 total
  const int bh = idx >> 14;
  const int d = (idx >> 8) & 63;
  const int j = idx & 255;
  const size_t base = (size_t)bh * NGRP * 65 * 256;
  float num = 0.f, cs = 0.f;
  #pragma unroll 6
  for (int g = 0; g < NGRP; ++g) {
    num += b2f(P[base + ((size_t)g * 65 + d) * 256 + j]);
    cs  += b2f(P[base + ((size_t)g * 65 + 64) * 256 + j]);
  }
  const float v = num / cs;
  const int b = bh >> 2, h = bh & 3;
  MO[((size_t)b * 256 + (d * 4 + h)) * 256 + j] = f2b(v);
}

// ---------------------------------------------------------------------------
// map output projection (tiny)
// ---------------------------------------------------------------------------
template<int DT>
DI void map_out_body(const void* __restrict__ Wmo, const uint16_t* __restrict__ MO,
                     void* __restrict__ out)
{
  const int o = blockIdx.x, bb = blockIdx.y, m = threadIdx.x;
  float acc = 0.f;
  #pragma unroll 8
  for (int c = 0; c < 256; ++c)
    acc += ld1<DT>(Wmo, (size_t)o * 256 + c) *
           b2f(MO[((size_t)bb * 256 + c) * 256 + m]);
  const size_t MAP_OFS = (size_t)4 * 256 * NTOK;
  st1<DT>(out, MAP_OFS + ((size_t)bb * 256 + o) * 256 + m, acc);
}
__global__ __launch_bounds__(256) void map_out_k(
    const void* Wmo, const uint16_t* MO, void* out, const int* __restrict__ flag)
{
  if (flag[0]) map_out_body<1>(Wmo, MO, out);
  else         map_out_body<0>(Wmo, MO, out);
}

extern "C" void kernel_launch(void* const* d_in, const int* in_sizes, int n_in,
                              void* d_out, int out_size, void* d_ws, size_t ws_size,
                              hipStream_t stream) {
  (void)in_sizes; (void)n_in; (void)out_size; (void)ws_size;
  const void* feat = d_in[0];
  const void* smap = d_in[1];
  const void* Wfqv = d_in[2];
  const void* Wmqv = d_in[3];
  const void* Wfo  = d_in[4];
  const void* Wmo  = d_in[5];
  char* ws = (char*)d_ws;

  const size_t BIG = (size_t)16 * 64 * NTOK * 2;   // 18,874,368 B
  const size_t SML = (size_t)16 * 256 * 64 * 2;    //    524,288 B
  const size_t FQ_OFF  = 0;                         // FO aliases FQ (token-major)
  const size_t FVT_OFF = FQ_OFF + BIG;
  const size_t MQ_OFF  = FVT_OFF + BIG;
  const size_t MVT_OFF = MQ_OFF + SML;
  const size_t MO_OFF  = MVT_OFF + SML;
  const size_t WQP_OFF = MO_OFF + (size_t)4 * 256 * 256 * 2;
  const size_t WFP_OFF = WQP_OFF + (size_t)512 * 256 * 2;
  const size_t FLAG_OFF = WFP_OFF + (size_t)256 * 256 * 2;

  uint16_t* FQ   = (uint16_t*)(ws + FQ_OFF);
  uint16_t* FVt  = (uint16_t*)(ws + FVT_OFF);
  uint16_t* MQ   = (uint16_t*)(ws + MQ_OFF);
  uint16_t* MVT  = (uint16_t*)(ws + MVT_OFF);
  uint16_t* MO   = (uint16_t*)(ws + MO_OFF);
  uint16_t* WqvP = (uint16_t*)(ws + WQP_OFF);
  uint16_t* WfoP = (uint16_t*)(ws + WFP_OFF);
  int* FLAG   = (int*)(ws + FLAG_OFF);

  // partial buffer P (16 bh x 36 grp x 65 rows x 256 j, bf16 = 19.17 MB)
  // lives in d_out: consumed by reduce_map BEFORE gemm1/map_out overwrite it.
  uint16_t* P = (uint16_t*)d_out;

  detect_dtype<<<dim3(1), dim3(64), 0, stream>>>((const uint32_t*)Wfqv, FLAG);
  prep_w<<<dim3(768), 256, 0, stream>>>(Wfqv, Wfo, WqvP, WfoP, FLAG);
  gemm0_mfma<<<dim3(144, 4), 256, 0, stream>>>(WqvP, feat, FQ, FVt, FLAG);
  map_qv<<<dim3(512, 4), 256, 0, stream>>>(Wmqv, smap, MQ, MVT, FLAG);
  attn_mfma<<<dim3(NGRP, 16), 256, 0, stream>>>(FQ, FVt, MQ, MVT, FQ, P);
  reduce_map<<<dim3(1024), 256, 0, stream>>>(P, MO);
  gemm1_mfma<<<dim3(36, 4, 4), 256, 0, stream>>>(WfoP, FQ, d_out, FLAG);
  map_out_k<<<dim3(256, 4), 256, 0, stream>>>(Wmo, MO, d_out, FLAG);
}

// Round 4
// 306.723 us; speedup vs baseline: 1.1319x; 1.1319x over previous
//
#include <hip/hip_runtime.h>
#include <stdint.h>

#define DI static __device__ __forceinline__

constexpr int NTOK = 9216;   // 96*96 feat tokens per batch
constexpr float ATT_SCALE = 0.125f;

typedef short bf16x8 __attribute__((ext_vector_type(8)));
typedef float f32x4  __attribute__((ext_vector_type(4)));

DI f32x4 mfma16(bf16x8 a, bf16x8 b, f32x4 c) {
  return __builtin_amdgcn_mfma_f32_16x16x32_bf16(a, b, c, 0, 0, 0);
}

DI float lo2f(uint32_t u) { union { uint32_t i; float f; } v; v.i = u << 16; return v.f; }
DI float hi2f(uint32_t u) { union { uint32_t i; float f; } v; v.i = u & 0xffff0000u; return v.f; }
DI float b2f(uint16_t u) { union { uint32_t i; float f; } v; v.i = ((uint32_t)u) << 16; return v.f; }
DI uint16_t f2b(float f) {
  union { float f; uint32_t i; } v; v.f = f;
  uint32_t r = (v.i + 0x7fffu + ((v.i >> 16) & 1u)) >> 16;
  return (uint16_t)r;
}

// ---- dtype-generic element access (DT: 1 = bf16 storage, 0 = fp32 storage) --
template<int DT> DI float ld1(const void* p, size_t off) {
  if constexpr (DT) return b2f(((const uint16_t*)p)[off]);
  else              return ((const float*)p)[off];
}
template<int DT> DI void st1(void* p, size_t off, float v) {
  if constexpr (DT) ((uint16_t*)p)[off] = f2b(v);
  else              ((float*)p)[off] = v;
}

// ---------------------------------------------------------------------------
// dtype detector (wave-parallel): flag=1 -> bf16 inputs, 0 -> fp32 inputs
// ---------------------------------------------------------------------------
__global__ void detect_dtype(const uint32_t* __restrict__ w, int* __restrict__ flag) {
  const int l = threadIdx.x;   // 64 lanes
  int cl = 0;
  #pragma unroll
  for (int i = 0; i < 4; ++i) {
    const float b = b2f((uint16_t)(w[l + i * 64] & 0xffffu));
    const float ab = fabsf(b);
    cl += (ab > 1e-4f && ab < 0.5f) ? 1 : 0;
  }
  cl += __shfl_xor(cl, 1);  cl += __shfl_xor(cl, 2);  cl += __shfl_xor(cl, 4);
  cl += __shfl_xor(cl, 8);  cl += __shfl_xor(cl, 16); cl += __shfl_xor(cl, 32);
  if (l == 0) flag[0] = (cl >= 128) ? 1 : 0;
}

// ---------------------------------------------------------------------------
// Weight prep (bf16, MFMA-ready), natural k-order.
// ---------------------------------------------------------------------------
template<int DT>
DI void prep_w_body(const void* __restrict__ Wfqv, const void* __restrict__ Wfo,
                    uint16_t* __restrict__ WqvP, uint16_t* __restrict__ WfoP)
{
  const int r = blockIdx.x, c = threadIdx.x;
  if (r < 512) {
    const int sel = r >> 8, within = r & 255;
    const int h = within >> 6, d = within & 63;
    const int src = sel * 256 + d * 4 + h;
    WqvP[(size_t)r * 256 + c] = f2b(ld1<DT>(Wfqv, (size_t)src * 256 + c));
  } else {
    const int ro = r - 512;
    WfoP[(size_t)ro * 256 + c] =
        f2b(ld1<DT>(Wfo, (size_t)ro * 256 + (c & 63) * 4 + (c >> 6)));
  }
}
__global__ __launch_bounds__(256) void prep_w(
    const void* Wfqv, const void* Wfo, uint16_t* WqvP, uint16_t* WfoP,
    const int* __restrict__ flag)
{
  if (flag[0]) prep_w_body<1>(Wfqv, Wfo, WqvP, WfoP);
  else         prep_w_body<0>(Wfqv, Wfo, WqvP, WfoP);
}

// ---------------------------------------------------------------------------
// GEMM0 (QV projection), MFMA. Grid (144 n-slabs, 4 batch), 256 thr.
// One block = 64 tokens x ALL 512 output channels (wave w = head w): feat
// fetched exactly once. X tile staged transposed once, barrier-free k-loop.
// ---------------------------------------------------------------------------
constexpr int P0 = 280;   // gemm0 LDS token-row pitch (elems)

template<int DT>
DI void gemm0_body(uint16_t* Xs, const uint16_t* __restrict__ WqvP,
                   const void* __restrict__ X,
                   uint16_t* __restrict__ FQ, uint16_t* __restrict__ FVt)
{
  const int tid = threadIdx.x;
  const int w = tid >> 6, lane = tid & 63;
  const int l = lane & 15, quad = lane >> 4;
  const int n0 = blockIdx.x * 64;
  const int bb = blockIdx.y;
  const size_t bh = (size_t)bb * 4 + w;    // wave w handles head w

  // ---- stage X[256k][64n] -> Xs[n][k] bf16, one shot
  {
    const int nh = (tid & 1) * 32;
    #pragma unroll
    for (int p = 0; p < 2; ++p) {
      const int c = p * 128 + (tid >> 1);
      const size_t g = ((size_t)bb * 256 + c) * NTOK + n0 + nh;
      if constexpr (DT) {
        #pragma unroll
        for (int u = 0; u < 4; ++u) {
          const uint4 v = *(const uint4*)((const uint16_t*)X + g + u * 8);
          const uint16_t* pk = (const uint16_t*)&v;
          #pragma unroll
          for (int j = 0; j < 8; ++j)
            Xs[(size_t)(nh + u * 8 + j) * P0 + c] = pk[j];
        }
      } else {
        #pragma unroll
        for (int u = 0; u < 8; ++u) {
          const float4 v = *(const float4*)((const float*)X + g + u * 4);
          Xs[(size_t)(nh + u * 4 + 0) * P0 + c] = f2b(v.x);
          Xs[(size_t)(nh + u * 4 + 1) * P0 + c] = f2b(v.y);
          Xs[(size_t)(nh + u * 4 + 2) * P0 + c] = f2b(v.z);
          Xs[(size_t)(nh + u * 4 + 3) * P0 + c] = f2b(v.w);
        }
      }
    }
  }
  __syncthreads();

  f32x4 acc[8][4];
  #pragma unroll
  for (int a = 0; a < 8; ++a)
    #pragma unroll
    for (int b = 0; b < 4; ++b) { acc[a][b].x = 0.f; acc[a][b].y = 0.f; acc[a][b].z = 0.f; acc[a][b].w = 0.f; }

  for (int ks = 0; ks < 8; ++ks) {
    bf16x8 af[8];
    #pragma unroll
    for (int mt = 0; mt < 8; ++mt) {
      const int arow = (mt >> 2) * 256 + w * 64 + (mt & 3) * 16 + l;
      af[mt] = *(const bf16x8*)(WqvP + (size_t)arow * 256 + ks * 32 + quad * 8);
    }
    #pragma unroll
    for (int nt = 0; nt < 4; ++nt) {
      const bf16x8 bv = *(const bf16x8*)(Xs + (size_t)(nt * 16 + l) * P0 + ks * 32 + quad * 8);
      #pragma unroll
      for (int mt = 0; mt < 8; ++mt)
        acc[mt][nt] = mfma16(af[mt], bv, acc[mt][nt]);
    }
  }
  #pragma unroll
  for (int mt = 0; mt < 8; ++mt)
    #pragma unroll
    for (int nt = 0; nt < 4; ++nt) {
      const int n = n0 + nt * 16 + l;
      if (mt < 4) {
        union { uint16_t h[4]; uint2 u; } pk;
        #pragma unroll
        for (int r = 0; r < 4; ++r) pk.h[r] = f2b(acc[mt][nt][r]);
        *(uint2*)(FQ + (bh * NTOK + n) * 64 + mt * 16 + quad * 4) = pk.u;
      } else {
        const int itile = n >> 5, io = n & 31;
        #pragma unroll
        for (int r = 0; r < 4; ++r)
          FVt[(((size_t)bh * 288 + itile) * 64 + (mt - 4) * 16 + quad * 4 + r) * 32 + io] =
              f2b(acc[mt][nt][r]);
      }
    }
}
__global__ __launch_bounds__(256) void gemm0_mfma(
    const uint16_t* WqvP, const void* X, uint16_t* FQ, uint16_t* FVt,
    const int* __restrict__ flag)
{
  __shared__ __align__(16) uint16_t Xs[64 * P0];
  if (flag[0]) gemm0_body<1>(Xs, WqvP, X, FQ, FVt);
  else         gemm0_body<0>(Xs, WqvP, X, FQ, FVt);
}

// ---------------------------------------------------------------------------
// GEMM1 (feat out projection), MFMA, LDS-free. Grid (36, 4 o-slabs, 4 b).
// ---------------------------------------------------------------------------
template<int DT>
DI void gemm1_body(const uint16_t* __restrict__ WfoP, const uint16_t* __restrict__ FO,
                   void* __restrict__ out)
{
  const int tid = threadIdx.x;
  const int w = tid >> 6, lane = tid & 63;
  const int l = lane & 15, quad = lane >> 4;
  const int n0 = blockIdx.x * 256;
  const int o0 = blockIdx.y * 64;
  const int bb = blockIdx.z;

  f32x4 acc[4][4];
  #pragma unroll
  for (int a = 0; a < 4; ++a)
    #pragma unroll
    for (int b = 0; b < 4; ++b) { acc[a][b].x = 0.f; acc[a][b].y = 0.f; acc[a][b].z = 0.f; acc[a][b].w = 0.f; }

  for (int ks = 0; ks < 8; ++ks) {
    const int h2 = ks >> 1;
    const int doff = (ks & 1) * 32 + quad * 8;
    bf16x8 af[4];
    #pragma unroll
    for (int mt = 0; mt < 4; ++mt)
      af[mt] = *(const bf16x8*)(WfoP + (size_t)(o0 + mt * 16 + l) * 256 + ks * 32 + quad * 8);
    #pragma unroll
    for (int nt = 0; nt < 4; ++nt) {
      const int n = n0 + w * 64 + nt * 16 + l;
      const bf16x8 bv = *(const bf16x8*)(FO + ((size_t)(bb * 4 + h2) * NTOK + n) * 64 + doff);
      #pragma unroll
      for (int mt = 0; mt < 4; ++mt)
        acc[mt][nt] = mfma16(af[mt], bv, acc[mt][nt]);
    }
  }
  #pragma unroll
  for (int mt = 0; mt < 4; ++mt)
    #pragma unroll
    for (int nt = 0; nt < 4; ++nt) {
      const int n = n0 + w * 64 + nt * 16 + l;
      #pragma unroll
      for (int r = 0; r < 4; ++r)
        st1<DT>(out, ((size_t)bb * 256 + o0 + mt * 16 + quad * 4 + r) * NTOK + n,
                acc[mt][nt][r]);
    }
}
__global__ __launch_bounds__(256) void gemm1_mfma(
    const uint16_t* WfoP, const uint16_t* FO, void* out,
    const int* __restrict__ flag)
{
  if (flag[0]) gemm1_body<1>(WfoP, FO, out);
  else         gemm1_body<0>(WfoP, FO, out);
}

// ---------------------------------------------------------------------------
// map QV projection (tiny): MQ[bh][m][d] token-major, MVT[bh][d][m] d-major
// ---------------------------------------------------------------------------
template<int DT>
DI void map_qv_body(const void* __restrict__ Wqv, const void* __restrict__ smap,
                    uint16_t* __restrict__ MQ, uint16_t* __restrict__ MVT)
{
  const int o = blockIdx.x, bb = blockIdx.y, m = threadIdx.x;
  float acc = 0.f;
  #pragma unroll 8
  for (int c = 0; c < 256; ++c)
    acc += ld1<DT>(Wqv, (size_t)o * 256 + c) *
           ld1<DT>(smap, (size_t)bb * 65536 + (size_t)c * 256 + m);
  const int oc = o & 255;
  const int h = oc & 3, d = oc >> 2;
  if (o < 256) MQ[(((size_t)bb * 4 + h) * 256 + m) * 64 + d] = f2b(acc);
  else         MVT[(((size_t)bb * 4 + h) * 64 + d) * 256 + m] = f2b(acc);
}
__global__ __launch_bounds__(256) void map_qv(
    const void* Wqv, const void* smap, uint16_t* MQ, uint16_t* MVT,
    const int* __restrict__ flag)
{
  if (flag[0]) map_qv_body<1>(Wqv, smap, MQ, MVT);
  else         map_qv_body<0>(Wqv, smap, MQ, MVT);
}

// ---------------------------------------------------------------------------
// Fused bidirectional attention, MFMA 16x16x32 bf16. Grid (72, 16).
// Round-4 fixes (post-mortem of round-3 spill disaster):
//  - __launch_bounds__(256,3): 168-reg budget fits 64 AGPR + ~100 VGPR,
//    no scratch (round-3's (256,4) spilled: WRITE 71->247 MB).
//  - Grid was the occupancy limiter (576 blk = 2.25/CU), NOT per-block
//    resources. NGRP 36->72: 1152 blocks = 4.5/CU, reg cap 3/CU now
//    binds -> ~12 waves/CU vs ~7.
//  - Keeps ETsh-free shuffle column phase (LDS 23 KB).
// ---------------------------------------------------------------------------
constexpr int PJ = 280;  // E[i][j] row pitch (560B rows, 16B-aligned)
constexpr int PO = 72;   // Osh row pitch (144 B: 16B-aligned, bank-spread)
constexpr int NGRP = 72; // partial groups (= blocks) per bh
constexpr int TPB = 4;   // i-tiles (of 32 tokens) per block = 288/NGRP

__global__ __launch_bounds__(256, 3) void attn_mfma(
    const uint16_t* __restrict__ FQ, const uint16_t* __restrict__ FVt,
    const uint16_t* __restrict__ MQ, const uint16_t* __restrict__ MVT,
    uint16_t* __restrict__ FO, uint16_t* __restrict__ P)
{
  __shared__ __align__(16) uint16_t Esh[32 * PJ];    // [i][j]  17,920 B
  __shared__ __align__(16) uint16_t Osh[32 * PO];    // [i][d]   4,608 B
  __shared__ float RS[4][32];                        //            512 B
  const int tid = threadIdx.x;
  const int w = tid >> 6;
  const int lane = tid & 63;
  const int l = lane & 15, quad = lane >> 4;
  const int blk = blockIdx.x, bh = blockIdx.y;
  const uint16_t* FQh  = FQ  + (size_t)bh * NTOK * 64;
  const uint16_t* FVth = FVt + (size_t)bh * 288 * 64 * 32;
  const uint16_t* MQh  = MQ  + (size_t)bh * 256 * 64;
  const uint16_t* MVTh = MVT + (size_t)bh * 64 * 256;
  uint16_t* FOh = FO + (size_t)bh * NTOK * 64;

  f32x4 numacc[4][4];
  #pragma unroll
  for (int a = 0; a < 4; ++a)
    #pragma unroll
    for (int b = 0; b < 4; ++b) { numacc[a][b].x = 0.f; numacc[a][b].y = 0.f; numacc[a][b].z = 0.f; numacc[a][b].w = 0.f; }
  float csum[4] = {0.f, 0.f, 0.f, 0.f};

  const int srcA = l + ((quad & 1) << 5);   // shuffle source lanes (col phase)
  const int srcB = srcA + 16;

  for (int t = 0; t < TPB; ++t) {
    const int it = blk * TPB + t;
    const int i0 = it * 32;

    // ---- QK phase: e_ij into Esh [i][j] + pku regs (col-phase source)
    bf16x8 qa[2][2];
    #pragma unroll
    for (int mt = 0; mt < 2; ++mt)
      #pragma unroll
      for (int kbi = 0; kbi < 2; ++kbi)
        qa[mt][kbi] = *(const bf16x8*)(FQh + (size_t)(i0 + mt * 16 + l) * 64 + kbi * 32 + quad * 8);

    uint2 pku[4][2];
    float rsum[2][4] = {{0.f,0.f,0.f,0.f},{0.f,0.f,0.f,0.f}};
    #pragma unroll
    for (int jt = 0; jt < 4; ++jt) {
      const int j0 = w * 64 + jt * 16;
      const bf16x8 kb0 = *(const bf16x8*)(MQh + (size_t)(j0 + l) * 64 + quad * 8);
      const bf16x8 kb1 = *(const bf16x8*)(MQh + (size_t)(j0 + l) * 64 + 32 + quad * 8);
      #pragma unroll
      for (int mt = 0; mt < 2; ++mt) {
        f32x4 acc = {0.f, 0.f, 0.f, 0.f};
        acc = mfma16(qa[mt][0], kb0, acc);
        acc = mfma16(qa[mt][1], kb1, acc);
        union { uint16_t h[4]; uint2 u; } pk;
        #pragma unroll
        for (int r = 0; r < 4; ++r) {
          const float e = __expf(acc[r] * ATT_SCALE);
          rsum[mt][r] += e;
          csum[jt] += e;
          pk.h[r] = f2b(e);
          Esh[(mt * 16 + quad * 4 + r) * PJ + j0 + l] = pk.h[r];
        }
        pku[jt][mt] = pk.u;
      }
    }

    // ---- issue this iter's FVt loads (consumed in col phase below)
    bf16x8 av[4];
    #pragma unroll
    for (int mt = 0; mt < 4; ++mt)
      av[mt] = *(const bf16x8*)(FVth + ((size_t)it * 64 + mt * 16 + l) * 32 + quad * 8);

    // ---- row-sum reduce -> RS (for row-phase normalization)
    #pragma unroll
    for (int mt = 0; mt < 2; ++mt)
      #pragma unroll
      for (int r = 0; r < 4; ++r) {
        float v = rsum[mt][r];
        v += __shfl_xor(v, 1); v += __shfl_xor(v, 2);
        v += __shfl_xor(v, 4); v += __shfl_xor(v, 8);
        if (l == 0) RS[w][mt * 16 + quad * 4 + r] = v;
      }

    // ---- column phase (pre-barrier, intra-wave): NUM^T[d][j] += V^T x E
    #pragma unroll
    for (int nt2 = 0; nt2 < 4; ++nt2) {
      const int a0 = __shfl((int)pku[nt2][0].x, srcA);
      const int a1 = __shfl((int)pku[nt2][0].y, srcA);
      const int a2 = __shfl((int)pku[nt2][0].x, srcB);
      const int a3 = __shfl((int)pku[nt2][0].y, srcB);
      const int b0 = __shfl((int)pku[nt2][1].x, srcA);
      const int b1 = __shfl((int)pku[nt2][1].y, srcA);
      const int b2 = __shfl((int)pku[nt2][1].x, srcB);
      const int b3 = __shfl((int)pku[nt2][1].y, srcB);
      const bool hi = (quad >> 1) != 0;
      union { int i[4]; bf16x8 v; } bu;
      bu.i[0] = hi ? b0 : a0;
      bu.i[1] = hi ? b1 : a1;
      bu.i[2] = hi ? b2 : a2;
      bu.i[3] = hi ? b3 : a3;
      #pragma unroll
      for (int mt = 0; mt < 4; ++mt)
        numacc[mt][nt2] = mfma16(av[mt], bu.v, numacc[mt][nt2]);
    }
    __syncthreads();

    // ---- row phase: feat_o^T[d][i] = MVT x E^T, normalized -> Osh
    {
      float rinv[2];
      #pragma unroll
      for (int nt = 0; nt < 2; ++nt) {
        const int i_ = nt * 16 + l;
        rinv[nt] = 1.f / (RS[0][i_] + RS[1][i_] + RS[2][i_] + RS[3][i_]);
      }
      f32x4 oacc[2];
      oacc[0].x=0.f;oacc[0].y=0.f;oacc[0].z=0.f;oacc[0].w=0.f;
      oacc[1]=oacc[0];
      #pragma unroll
      for (int ks = 0; ks < 8; ++ks) {
        const bf16x8 avr = *(const bf16x8*)(MVTh + (size_t)(w * 16 + l) * 256 + ks * 32 + quad * 8);
        #pragma unroll
        for (int nt = 0; nt < 2; ++nt) {
          const bf16x8 bv = *(const bf16x8*)(Esh + (size_t)(nt * 16 + l) * PJ + ks * 32 + quad * 8);
          oacc[nt] = mfma16(avr, bv, oacc[nt]);
        }
      }
      #pragma unroll
      for (int nt = 0; nt < 2; ++nt) {
        union { uint16_t h[4]; uint2 u; } pk;
        #pragma unroll
        for (int r = 0; r < 4; ++r) pk.h[r] = f2b(oacc[nt][r] * rinv[nt]);
        *(uint2*)(Osh + (nt * 16 + l) * PO + w * 16 + quad * 4) = pk.u;
      }
    }
    __syncthreads();

    // ---- FO write: full 128-B line per token (8 thr x uint4)
    {
      const int ti = tid >> 3, c = tid & 7;
      *(uint4*)(FOh + (size_t)(i0 + ti) * 64 + c * 8) =
          *(const uint4*)(Osh + ti * PO + c * 8);
    }
  }

  // ---- flush partials (plain bf16 stores, no atomics)
  uint16_t* Pb = P + ((size_t)bh * NGRP + blk) * 65 * 256;
  #pragma unroll
  for (int mt = 0; mt < 4; ++mt)
    #pragma unroll
    for (int nt2 = 0; nt2 < 4; ++nt2)
      #pragma unroll
      for (int r = 0; r < 4; ++r)
        Pb[(mt * 16 + quad * 4 + r) * 256 + w * 64 + nt2 * 16 + l] =
            f2b(numacc[mt][nt2][r]);
  #pragma unroll
  for (int jt = 0; jt < 4; ++jt) {
    float v = csum[jt];
    v += __shfl_xor(v, 16); v += __shfl_xor(v, 32);
    if (quad == 0) Pb[64 * 256 + w * 64 + jt * 16 + l] = f2b(v);
  }
}

// ---------------------------------------------------------------------------
// reduce partials -> map_o: MO[b][c=d*4+h][j] = sum_g NUM / sum_g CS
// ---------------------------------------------------------------------------
__global__ __launch_bounds__(256) void reduce_map(
    const uint16_t* __restrict__ P, uint16_t* __restrict__ MO)
{
  const int idx = blockIdx.x * 256 + threadIdx.x;   // 262144 total
  const int bh = idx >> 14;
  const int d = (idx >> 8) & 63;
  const int j = idx & 255;
  const size_t base = (size_t)bh * NGRP * 65 * 256;
  float num = 0.f, cs = 0.f;
  #pragma unroll 6
  for (int g = 0; g < NGRP; ++g) {
    num += b2f(P[base + ((size_t)g * 65 + d) * 256 + j]);
    cs  += b2f(P[base + ((size_t)g * 65 + 64) * 256 + j]);
  }
  const float v = num / cs;
  const int b = bh >> 2, h = bh & 3;
  MO[((size_t)b * 256 + (d * 4 + h)) * 256 + j] = f2b(v);
}

// ---------------------------------------------------------------------------
// map output projection (tiny)
// ---------------------------------------------------------------------------
template<int DT>
DI void map_out_body(const void* __restrict__ Wmo, const uint16_t* __restrict__ MO,
                     void* __restrict__ out)
{
  const int o = blockIdx.x, bb = blockIdx.y, m = threadIdx.x;
  float acc = 0.f;
  #pragma unroll 8
  for (int c = 0; c < 256; ++c)
    acc += ld1<DT>(Wmo, (size_t)o * 256 + c) *
           b2f(MO[((size_t)bb * 256 + c) * 256 + m]);
  const size_t MAP_OFS = (size_t)4 * 256 * NTOK;
  st1<DT>(out, MAP_OFS + ((size_t)bb * 256 + o) * 256 + m, acc);
}
__global__ __launch_bounds__(256) void map_out_k(
    const void* Wmo, const uint16_t* MO, void* out, const int* __restrict__ flag)
{
  if (flag[0]) map_out_body<1>(Wmo, MO, out);
  else         map_out_body<0>(Wmo, MO, out);
}

extern "C" void kernel_launch(void* const* d_in, const int* in_sizes, int n_in,
                              void* d_out, int out_size, void* d_ws, size_t ws_size,
                              hipStream_t stream) {
  (void)in_sizes; (void)n_in; (void)out_size; (void)ws_size;
  const void* feat = d_in[0];
  const void* smap = d_in[1];
  const void* Wfqv = d_in[2];
  const void* Wmqv = d_in[3];
  const void* Wfo  = d_in[4];
  const void* Wmo  = d_in[5];
  char* ws = (char*)d_ws;

  const size_t BIG = (size_t)16 * 64 * NTOK * 2;   // 18,874,368 B
  const size_t SML = (size_t)16 * 256 * 64 * 2;    //    524,288 B
  const size_t FQ_OFF  = 0;                         // FO aliases FQ (token-major)
  const size_t FVT_OFF = FQ_OFF + BIG;
  const size_t MQ_OFF  = FVT_OFF + BIG;
  const size_t MVT_OFF = MQ_OFF + SML;
  const size_t MO_OFF  = MVT_OFF + SML;
  const size_t WQP_OFF = MO_OFF + (size_t)4 * 256 * 256 * 2;
  const size_t WFP_OFF = WQP_OFF + (size_t)512 * 256 * 2;
  const size_t FLAG_OFF = WFP_OFF + (size_t)256 * 256 * 2;

  uint16_t* FQ   = (uint16_t*)(ws + FQ_OFF);
  uint16_t* FVt  = (uint16_t*)(ws + FVT_OFF);
  uint16_t* MQ   = (uint16_t*)(ws + MQ_OFF);
  uint16_t* MVT  = (uint16_t*)(ws + MVT_OFF);
  uint16_t* MO   = (uint16_t*)(ws + MO_OFF);
  uint16_t* WqvP = (uint16_t*)(ws + WQP_OFF);
  uint16_t* WfoP = (uint16_t*)(ws + WFP_OFF);
  int* FLAG   = (int*)(ws + FLAG_OFF);

  // partial buffer P (16 bh x 72 grp x 65 rows x 256 j, bf16 = 38.34 MB)
  // lives in d_out (38.80 MB): consumed by reduce_map BEFORE gemm1/map_out
  // overwrite it (stream-ordered).
  uint16_t* P = (uint16_t*)d_out;

  detect_dtype<<<dim3(1), dim3(64), 0, stream>>>((const uint32_t*)Wfqv, FLAG);
  prep_w<<<dim3(768), 256, 0, stream>>>(Wfqv, Wfo, WqvP, WfoP, FLAG);
  gemm0_mfma<<<dim3(144, 4), 256, 0, stream>>>(WqvP, feat, FQ, FVt, FLAG);
  map_qv<<<dim3(512, 4), 256, 0, stream>>>(Wmqv, smap, MQ, MVT, FLAG);
  attn_mfma<<<dim3(NGRP, 16), 256, 0, stream>>>(FQ, FVt, MQ, MVT, FQ, P);
  reduce_map<<<dim3(1024), 256, 0, stream>>>(P, MO);
  gemm1_mfma<<<dim3(36, 4, 4), 256, 0, stream>>>(WfoP, FQ, d_out, FLAG);
  map_out_k<<<dim3(256, 4), 256, 0, stream>>>(Wmo, MO, d_out, FLAG);
}

// Round 5
// 286.793 us; speedup vs baseline: 1.2105x; 1.0695x over previous
//
#include <hip/hip_runtime.h>
#include <stdint.h>

#define DI static __device__ __forceinline__

constexpr int NTOK = 9216;   // 96*96 feat tokens per batch
constexpr float ATT_SCALE = 0.125f;

typedef short bf16x8 __attribute__((ext_vector_type(8)));
typedef float f32x4  __attribute__((ext_vector_type(4)));

DI f32x4 mfma16(bf16x8 a, bf16x8 b, f32x4 c) {
  return __builtin_amdgcn_mfma_f32_16x16x32_bf16(a, b, c, 0, 0, 0);
}

DI float lo2f(uint32_t u) { union { uint32_t i; float f; } v; v.i = u << 16; return v.f; }
DI float hi2f(uint32_t u) { union { uint32_t i; float f; } v; v.i = u & 0xffff0000u; return v.f; }
DI float b2f(uint16_t u) { union { uint32_t i; float f; } v; v.i = ((uint32_t)u) << 16; return v.f; }
DI uint16_t f2b(float f) {
  union { float f; uint32_t i; } v; v.f = f;
  uint32_t r = (v.i + 0x7fffu + ((v.i >> 16) & 1u)) >> 16;
  return (uint16_t)r;
}

// ---- dtype-generic element access (DT: 1 = bf16 storage, 0 = fp32 storage) --
template<int DT> DI float ld1(const void* p, size_t off) {
  if constexpr (DT) return b2f(((const uint16_t*)p)[off]);
  else              return ((const float*)p)[off];
}
template<int DT> DI void st1(void* p, size_t off, float v) {
  if constexpr (DT) ((uint16_t*)p)[off] = f2b(v);
  else              ((float*)p)[off] = v;
}

// ---------------------------------------------------------------------------
// dtype detector (wave-parallel): flag=1 -> bf16 inputs, 0 -> fp32 inputs
// ---------------------------------------------------------------------------
__global__ void detect_dtype(const uint32_t* __restrict__ w, int* __restrict__ flag) {
  const int l = threadIdx.x;   // 64 lanes
  int cl = 0;
  #pragma unroll
  for (int i = 0; i < 4; ++i) {
    const float b = b2f((uint16_t)(w[l + i * 64] & 0xffffu));
    const float ab = fabsf(b);
    cl += (ab > 1e-4f && ab < 0.5f) ? 1 : 0;
  }
  cl += __shfl_xor(cl, 1);  cl += __shfl_xor(cl, 2);  cl += __shfl_xor(cl, 4);
  cl += __shfl_xor(cl, 8);  cl += __shfl_xor(cl, 16); cl += __shfl_xor(cl, 32);
  if (l == 0) flag[0] = (cl >= 128) ? 1 : 0;
}

// ---------------------------------------------------------------------------
// Weight prep (bf16, MFMA-ready), natural k-order.
// ---------------------------------------------------------------------------
template<int DT>
DI void prep_w_body(const void* __restrict__ Wfqv, const void* __restrict__ Wfo,
                    uint16_t* __restrict__ WqvP, uint16_t* __restrict__ WfoP)
{
  const int r = blockIdx.x, c = threadIdx.x;
  if (r < 512) {
    const int sel = r >> 8, within = r & 255;
    const int h = within >> 6, d = within & 63;
    const int src = sel * 256 + d * 4 + h;
    WqvP[(size_t)r * 256 + c] = f2b(ld1<DT>(Wfqv, (size_t)src * 256 + c));
  } else {
    const int ro = r - 512;
    WfoP[(size_t)ro * 256 + c] =
        f2b(ld1<DT>(Wfo, (size_t)ro * 256 + (c & 63) * 4 + (c >> 6)));
  }
}
__global__ __launch_bounds__(256) void prep_w(
    const void* Wfqv, const void* Wfo, uint16_t* WqvP, uint16_t* WfoP,
    const int* __restrict__ flag)
{
  if (flag[0]) prep_w_body<1>(Wfqv, Wfo, WqvP, WfoP);
  else         prep_w_body<0>(Wfqv, Wfo, WqvP, WfoP);
}

// ---------------------------------------------------------------------------
// GEMM0 (QV projection), MFMA. Grid (144 n-slabs, 4 batch), 256 thr.
// One block = 64 tokens x ALL 512 output channels (wave w = head w): feat
// fetched exactly once. Round-5: staging vectorized — each thread owns 2
// token-rows and writes k-octets via ds_write_b128 (was 64 scalar u16
// writes/thread). Global reads stay coalesced (float2/uint32 per lane).
// ---------------------------------------------------------------------------
constexpr int P0 = 280;   // gemm0 LDS token-row pitch (elems)

template<int DT>
DI void gemm0_body(uint16_t* Xs, const uint16_t* __restrict__ WqvP,
                   const void* __restrict__ X,
                   uint16_t* __restrict__ FQ, uint16_t* __restrict__ FVt)
{
  const int tid = threadIdx.x;
  const int w = tid >> 6, lane = tid & 63;
  const int l = lane & 15, quad = lane >> 4;
  const int n0 = blockIdx.x * 64;
  const int bb = blockIdx.y;
  const size_t bh = (size_t)bb * 4 + w;    // wave w handles head w

  // ---- stage X[256k][64n] -> Xs[n][k] bf16: thread owns rows nb,nb+1,
  // k-octet kg*8 per pass; 8 coalesced loads -> 2x ds_write_b128.
  {
    const int nb = (tid & 31) * 2;       // 2 n-rows per thread
    const int kg = tid >> 5;             // 0..7 k-octet group
    #pragma unroll
    for (int pass = 0; pass < 4; ++pass) {
      const int k0 = pass * 64 + kg * 8;
      union { uint16_t h[8]; uint4 u; } pk0, pk1;
      #pragma unroll
      for (int j = 0; j < 8; ++j) {
        const size_t g = ((size_t)bb * 256 + k0 + j) * NTOK + n0 + nb;
        if constexpr (DT) {
          const uint32_t v = *(const uint32_t*)((const uint16_t*)X + g);
          pk0.h[j] = (uint16_t)(v & 0xffffu);
          pk1.h[j] = (uint16_t)(v >> 16);
        } else {
          const float2 v = *(const float2*)((const float*)X + g);
          pk0.h[j] = f2b(v.x);
          pk1.h[j] = f2b(v.y);
        }
      }
      *(uint4*)(Xs + (size_t)(nb + 0) * P0 + k0) = pk0.u;
      *(uint4*)(Xs + (size_t)(nb + 1) * P0 + k0) = pk1.u;
    }
  }
  __syncthreads();

  f32x4 acc[8][4];
  #pragma unroll
  for (int a = 0; a < 8; ++a)
    #pragma unroll
    for (int b = 0; b < 4; ++b) { acc[a][b].x = 0.f; acc[a][b].y = 0.f; acc[a][b].z = 0.f; acc[a][b].w = 0.f; }

  for (int ks = 0; ks < 8; ++ks) {
    bf16x8 af[8];
    #pragma unroll
    for (int mt = 0; mt < 8; ++mt) {
      const int arow = (mt >> 2) * 256 + w * 64 + (mt & 3) * 16 + l;
      af[mt] = *(const bf16x8*)(WqvP + (size_t)arow * 256 + ks * 32 + quad * 8);
    }
    #pragma unroll
    for (int nt = 0; nt < 4; ++nt) {
      const bf16x8 bv = *(const bf16x8*)(Xs + (size_t)(nt * 16 + l) * P0 + ks * 32 + quad * 8);
      #pragma unroll
      for (int mt = 0; mt < 8; ++mt)
        acc[mt][nt] = mfma16(af[mt], bv, acc[mt][nt]);
    }
  }
  #pragma unroll
  for (int mt = 0; mt < 8; ++mt)
    #pragma unroll
    for (int nt = 0; nt < 4; ++nt) {
      const int n = n0 + nt * 16 + l;
      if (mt < 4) {
        union { uint16_t h[4]; uint2 u; } pk;
        #pragma unroll
        for (int r = 0; r < 4; ++r) pk.h[r] = f2b(acc[mt][nt][r]);
        *(uint2*)(FQ + (bh * NTOK + n) * 64 + mt * 16 + quad * 4) = pk.u;
      } else {
        const int itile = n >> 5, io = n & 31;
        #pragma unroll
        for (int r = 0; r < 4; ++r)
          FVt[(((size_t)bh * 288 + itile) * 64 + (mt - 4) * 16 + quad * 4 + r) * 32 + io] =
              f2b(acc[mt][nt][r]);
      }
    }
}
__global__ __launch_bounds__(256) void gemm0_mfma(
    const uint16_t* WqvP, const void* X, uint16_t* FQ, uint16_t* FVt,
    const int* __restrict__ flag)
{
  __shared__ __align__(16) uint16_t Xs[64 * P0];
  if (flag[0]) gemm0_body<1>(Xs, WqvP, X, FQ, FVt);
  else         gemm0_body<0>(Xs, WqvP, X, FQ, FVt);
}

// ---------------------------------------------------------------------------
// GEMM1 (feat out projection), MFMA, LDS-free. Grid (36, 4 o-slabs, 4 b).
// Round-5: ks loop fully unrolled so af/bv loads pipeline across iterations.
// ---------------------------------------------------------------------------
template<int DT>
DI void gemm1_body(const uint16_t* __restrict__ WfoP, const uint16_t* __restrict__ FO,
                   void* __restrict__ out)
{
  const int tid = threadIdx.x;
  const int w = tid >> 6, lane = tid & 63;
  const int l = lane & 15, quad = lane >> 4;
  const int n0 = blockIdx.x * 256;
  const int o0 = blockIdx.y * 64;
  const int bb = blockIdx.z;

  f32x4 acc[4][4];
  #pragma unroll
  for (int a = 0; a < 4; ++a)
    #pragma unroll
    for (int b = 0; b < 4; ++b) { acc[a][b].x = 0.f; acc[a][b].y = 0.f; acc[a][b].z = 0.f; acc[a][b].w = 0.f; }

  #pragma unroll
  for (int ks = 0; ks < 8; ++ks) {
    const int h2 = ks >> 1;
    const int doff = (ks & 1) * 32 + quad * 8;
    bf16x8 af[4];
    #pragma unroll
    for (int mt = 0; mt < 4; ++mt)
      af[mt] = *(const bf16x8*)(WfoP + (size_t)(o0 + mt * 16 + l) * 256 + ks * 32 + quad * 8);
    #pragma unroll
    for (int nt = 0; nt < 4; ++nt) {
      const int n = n0 + w * 64 + nt * 16 + l;
      const bf16x8 bv = *(const bf16x8*)(FO + ((size_t)(bb * 4 + h2) * NTOK + n) * 64 + doff);
      #pragma unroll
      for (int mt = 0; mt < 4; ++mt)
        acc[mt][nt] = mfma16(af[mt], bv, acc[mt][nt]);
    }
  }
  #pragma unroll
  for (int mt = 0; mt < 4; ++mt)
    #pragma unroll
    for (int nt = 0; nt < 4; ++nt) {
      const int n = n0 + w * 64 + nt * 16 + l;
      #pragma unroll
      for (int r = 0; r < 4; ++r)
        st1<DT>(out, ((size_t)bb * 256 + o0 + mt * 16 + quad * 4 + r) * NTOK + n,
                acc[mt][nt][r]);
    }
}
__global__ __launch_bounds__(256) void gemm1_mfma(
    const uint16_t* WfoP, const uint16_t* FO, void* out,
    const int* __restrict__ flag)
{
  if (flag[0]) gemm1_body<1>(WfoP, FO, out);
  else         gemm1_body<0>(WfoP, FO, out);
}

// ---------------------------------------------------------------------------
// map QV projection (tiny): MQ[bh][m][d] token-major, MVT[bh][d][m] d-major
// ---------------------------------------------------------------------------
template<int DT>
DI void map_qv_body(const void* __restrict__ Wqv, const void* __restrict__ smap,
                    uint16_t* __restrict__ MQ, uint16_t* __restrict__ MVT)
{
  const int o = blockIdx.x, bb = blockIdx.y, m = threadIdx.x;
  float acc = 0.f;
  #pragma unroll 8
  for (int c = 0; c < 256; ++c)
    acc += ld1<DT>(Wqv, (size_t)o * 256 + c) *
           ld1<DT>(smap, (size_t)bb * 65536 + (size_t)c * 256 + m);
  const int oc = o & 255;
  const int h = oc & 3, d = oc >> 2;
  if (o < 256) MQ[(((size_t)bb * 4 + h) * 256 + m) * 64 + d] = f2b(acc);
  else         MVT[(((size_t)bb * 4 + h) * 64 + d) * 256 + m] = f2b(acc);
}
__global__ __launch_bounds__(256) void map_qv(
    const void* Wqv, const void* smap, uint16_t* MQ, uint16_t* MVT,
    const int* __restrict__ flag)
{
  if (flag[0]) map_qv_body<1>(Wqv, smap, MQ, MVT);
  else         map_qv_body<0>(Wqv, smap, MQ, MVT);
}

// ---------------------------------------------------------------------------
// Fused bidirectional attention, MFMA 16x16x32 bf16. Grid (36, 16).
// Round-5: EXACT revert to the round-2 configuration (measured 98 us —
// best of rounds 1-4). NGRP=36, ETsh present, (256,3), kb/avr hoist
// (compiler sinks it; measured fine), av issued between barrier and row
// phase. Three variation attempts (R1 prefetch burst, R3 shuffle+reg
// squeeze, R4 NGRP=72) all regressed; this is the measured optimum of
// this structure.
// ---------------------------------------------------------------------------
constexpr int PJ = 280;  // E[i][j] row pitch (560B rows, 16B-aligned)
constexpr int PI = 40;   // ET[j][i] row pitch (80B rows, 16B-aligned)
constexpr int PO = 72;   // Osh row pitch (144 B: 16B-aligned, bank-spread)
constexpr int NGRP = 36; // partial groups (= blocks) per bh

__global__ __launch_bounds__(256, 3) void attn_mfma(
    const uint16_t* __restrict__ FQ, const uint16_t* __restrict__ FVt,
    const uint16_t* __restrict__ MQ, const uint16_t* __restrict__ MVT,
    uint16_t* __restrict__ FO, uint16_t* __restrict__ P)
{
  __shared__ __align__(16) uint16_t Esh[32 * PJ];    // [i][j]
  __shared__ __align__(16) uint16_t ETsh[256 * PI];  // [j][i]
  __shared__ __align__(16) uint16_t Osh[32 * PO];    // [i][d] out-staging
  __shared__ float RS[4][32];
  const int tid = threadIdx.x;
  const int w = tid >> 6;
  const int lane = tid & 63;
  const int l = lane & 15, quad = lane >> 4;
  const int blk = blockIdx.x, bh = blockIdx.y;
  const uint16_t* FQh  = FQ  + (size_t)bh * NTOK * 64;
  const uint16_t* FVth = FVt + (size_t)bh * 288 * 64 * 32;
  const uint16_t* MQh  = MQ  + (size_t)bh * 256 * 64;
  const uint16_t* MVTh = MVT + (size_t)bh * 64 * 256;
  uint16_t* FOh = FO + (size_t)bh * NTOK * 64;

  // ---- hoisted loop-invariant operand fragments (live whole kernel) ----
  bf16x8 kb[4][2];   // MQ: wave w's 64 map-tokens, both k-halves
  #pragma unroll
  for (int jt = 0; jt < 4; ++jt) {
    const int j = w * 64 + jt * 16 + l;
    kb[jt][0] = *(const bf16x8*)(MQh + (size_t)j * 64 + quad * 8);
    kb[jt][1] = *(const bf16x8*)(MQh + (size_t)j * 64 + 32 + quad * 8);
  }
  bf16x8 avr[8];     // MVT: wave w's 16 d-rows, all 8 k-slices
  #pragma unroll
  for (int ks = 0; ks < 8; ++ks)
    avr[ks] = *(const bf16x8*)(MVTh + (size_t)(w * 16 + l) * 256 + ks * 32 + quad * 8);

  f32x4 numacc[4][4];
  #pragma unroll
  for (int a = 0; a < 4; ++a)
    #pragma unroll
    for (int b = 0; b < 4; ++b) { numacc[a][b].x = 0.f; numacc[a][b].y = 0.f; numacc[a][b].z = 0.f; numacc[a][b].w = 0.f; }
  float csum[4] = {0.f, 0.f, 0.f, 0.f};

  for (int t = 0; t < 8; ++t) {
    const int it = blk * 8 + t;
    const int i0 = it * 32;

    // ---- QK phase: e_ij into Esh [i][j] and ETsh [j][i]
    bf16x8 qa[2][2];
    #pragma unroll
    for (int mt = 0; mt < 2; ++mt)
      #pragma unroll
      for (int kbi = 0; kbi < 2; ++kbi)
        qa[mt][kbi] = *(const bf16x8*)(FQh + (size_t)(i0 + mt * 16 + l) * 64 + kbi * 32 + quad * 8);

    float rsum[2][4] = {{0.f,0.f,0.f,0.f},{0.f,0.f,0.f,0.f}};
    #pragma unroll
    for (int jt = 0; jt < 4; ++jt) {
      const int j0 = w * 64 + jt * 16;
      #pragma unroll
      for (int mt = 0; mt < 2; ++mt) {
        f32x4 acc = {0.f, 0.f, 0.f, 0.f};
        acc = mfma16(qa[mt][0], kb[jt][0], acc);
        acc = mfma16(qa[mt][1], kb[jt][1], acc);
        union { uint16_t h[4]; uint2 u; } pk;
        #pragma unroll
        for (int r = 0; r < 4; ++r) {
          const float e = __expf(acc[r] * ATT_SCALE);
          rsum[mt][r] += e;
          csum[jt] += e;
          pk.h[r] = f2b(e);
          Esh[(mt * 16 + quad * 4 + r) * PJ + j0 + l] = pk.h[r];
        }
        *(uint2*)(ETsh + (size_t)(j0 + l) * PI + mt * 16 + quad * 4) = pk.u;
      }
    }
    #pragma unroll
    for (int mt = 0; mt < 2; ++mt)
      #pragma unroll
      for (int r = 0; r < 4; ++r) {
        float v = rsum[mt][r];
        v += __shfl_xor(v, 1); v += __shfl_xor(v, 2);
        v += __shfl_xor(v, 4); v += __shfl_xor(v, 8);
        if (l == 0) RS[w][mt * 16 + quad * 4 + r] = v;
      }
    __syncthreads();

    // ---- issue column-phase FVt loads; row phase below covers their latency
    bf16x8 av[4];
    #pragma unroll
    for (int mt = 0; mt < 4; ++mt)
      av[mt] = *(const bf16x8*)(FVth + ((size_t)it * 64 + mt * 16 + l) * 32 + quad * 8);

    // ---- row phase: feat_o^T[d][i] = MVT x E^T, normalized -> Osh
    {
      float rinv[2];
      #pragma unroll
      for (int nt = 0; nt < 2; ++nt) {
        const int i_ = nt * 16 + l;
        rinv[nt] = 1.f / (RS[0][i_] + RS[1][i_] + RS[2][i_] + RS[3][i_]);
      }
      f32x4 oacc[2];
      oacc[0].x=0.f;oacc[0].y=0.f;oacc[0].z=0.f;oacc[0].w=0.f;
      oacc[1]=oacc[0];
      #pragma unroll
      for (int ks = 0; ks < 8; ++ks) {
        #pragma unroll
        for (int nt = 0; nt < 2; ++nt) {
          const bf16x8 bv = *(const bf16x8*)(Esh + (size_t)(nt * 16 + l) * PJ + ks * 32 + quad * 8);
          oacc[nt] = mfma16(avr[ks], bv, oacc[nt]);
        }
      }
      #pragma unroll
      for (int nt = 0; nt < 2; ++nt) {
        union { uint16_t h[4]; uint2 u; } pk;
        #pragma unroll
        for (int r = 0; r < 4; ++r) pk.h[r] = f2b(oacc[nt][r] * rinv[nt]);
        *(uint2*)(Osh + (nt * 16 + l) * PO + w * 16 + quad * 4) = pk.u;
      }
    }

    // ---- column phase: NUM^T[d][j] += FVt-tile x E (regs across tiles)
    #pragma unroll
    for (int mt = 0; mt < 4; ++mt) {
      #pragma unroll
      for (int nt2 = 0; nt2 < 4; ++nt2) {
        const bf16x8 bv = *(const bf16x8*)(ETsh + (size_t)(w * 64 + nt2 * 16 + l) * PI + quad * 8);
        numacc[mt][nt2] = mfma16(av[mt], bv, numacc[mt][nt2]);
      }
    }
    __syncthreads();

    // ---- FO write: full 128-B line per token (8 thr x uint4)
    {
      const int ti = tid >> 3, c = tid & 7;
      *(uint4*)(FOh + (size_t)(i0 + ti) * 64 + c * 8) =
          *(const uint4*)(Osh + ti * PO + c * 8);
    }
  }

  // ---- flush partials (plain bf16 stores, no atomics)
  uint16_t* Pb = P + ((size_t)bh * NGRP + blk) * 65 * 256;
  #pragma unroll
  for (int mt = 0; mt < 4; ++mt)
    #pragma unroll
    for (int nt2 = 0; nt2 < 4; ++nt2)
      #pragma unroll
      for (int r = 0; r < 4; ++r)
        Pb[(mt * 16 + quad * 4 + r) * 256 + w * 64 + nt2 * 16 + l] =
            f2b(numacc[mt][nt2][r]);
  #pragma unroll
  for (int jt = 0; jt < 4; ++jt) {
    float v = csum[jt];
    v += __shfl_xor(v, 16); v += __shfl_xor(v, 32);
    if (quad == 0) Pb[64 * 256 + w * 64 + jt * 16 + l] = f2b(v);
  }
}

// ---------------------------------------------------------------------------
// reduce partials -> map_o: MO[b][c=d*4+h][j] = sum_g NUM / sum_g CS
// ---------------------------------------------------------------------------
__global__ __launch_bounds__(256) void reduce_map(
    const uint16_t* __restrict__ P, uint16_t* __restrict__ MO)
{
  const int idx = blockIdx.x * 256 + threadIdx.x;   // 262144 total
  const int bh = idx >> 14;
  const int d = (idx >> 8) & 63;
  const int j = idx & 255;
  const size_t base = (size_t)bh * NGRP * 65 * 256;
  float num = 0.f, cs = 0.f;
  #pragma unroll 6
  for (int g = 0; g < NGRP; ++g) {
    num += b2f(P[base + ((size_t)g * 65 + d) * 256 + j]);
    cs  += b2f(P[base + ((size_t)g * 65 + 64) * 256 + j]);
  }
  const float v = num / cs;
  const int b = bh >> 2, h = bh & 3;
  MO[((size_t)b * 256 + (d * 4 + h)) * 256 + j] = f2b(v);
}

// ---------------------------------------------------------------------------
// map output projection (tiny)
// ---------------------------------------------------------------------------
template<int DT>
DI void map_out_body(const void* __restrict__ Wmo, const uint16_t* __restrict__ MO,
                     void* __restrict__ out)
{
  const int o = blockIdx.x, bb = blockIdx.y, m = threadIdx.x;
  float acc = 0.f;
  #pragma unroll 8
  for (int c = 0; c < 256; ++c)
    acc += ld1<DT>(Wmo, (size_t)o * 256 + c) *
           b2f(MO[((size_t)bb * 256 + c) * 256 + m]);
  const size_t MAP_OFS = (size_t)4 * 256 * NTOK;
  st1<DT>(out, MAP_OFS + ((size_t)bb * 256 + o) * 256 + m, acc);
}
__global__ __launch_bounds__(256) void map_out_k(
    const void* Wmo, const uint16_t* MO, void* out, const int* __restrict__ flag)
{
  if (flag[0]) map_out_body<1>(Wmo, MO, out);
  else         map_out_body<0>(Wmo, MO, out);
}

extern "C" void kernel_launch(void* const* d_in, const int* in_sizes, int n_in,
                              void* d_out, int out_size, void* d_ws, size_t ws_size,
                              hipStream_t stream) {
  (void)in_sizes; (void)n_in; (void)out_size; (void)ws_size;
  const void* feat = d_in[0];
  const void* smap = d_in[1];
  const void* Wfqv = d_in[2];
  const void* Wmqv = d_in[3];
  const void* Wfo  = d_in[4];
  const void* Wmo  = d_in[5];
  char* ws = (char*)d_ws;

  const size_t BIG = (size_t)16 * 64 * NTOK * 2;   // 18,874,368 B
  const size_t SML = (size_t)16 * 256 * 64 * 2;    //    524,288 B
  const size_t FQ_OFF  = 0;                         // FO aliases FQ (token-major)
  const size_t FVT_OFF = FQ_OFF + BIG;
  const size_t MQ_OFF  = FVT_OFF + BIG;
  const size_t MVT_OFF = MQ_OFF + SML;
  const size_t MO_OFF  = MVT_OFF + SML;
  const size_t WQP_OFF = MO_OFF + (size_t)4 * 256 * 256 * 2;
  const size_t WFP_OFF = WQP_OFF + (size_t)512 * 256 * 2;
  const size_t FLAG_OFF = WFP_OFF + (size_t)256 * 256 * 2;

  uint16_t* FQ   = (uint16_t*)(ws + FQ_OFF);
  uint16_t* FVt  = (uint16_t*)(ws + FVT_OFF);
  uint16_t* MQ   = (uint16_t*)(ws + MQ_OFF);
  uint16_t* MVT  = (uint16_t*)(ws + MVT_OFF);
  uint16_t* MO   = (uint16_t*)(ws + MO_OFF);
  uint16_t* WqvP = (uint16_t*)(ws + WQP_OFF);
  uint16_t* WfoP = (uint16_t*)(ws + WFP_OFF);
  int* FLAG   = (int*)(ws + FLAG_OFF);

  // partial buffer P (16 bh x 36 grp x 65 rows x 256 j, bf16 = 19.17 MB)
  // lives in d_out: consumed by reduce_map BEFORE gemm1/map_out overwrite it.
  uint16_t* P = (uint16_t*)d_out;

  detect_dtype<<<dim3(1), dim3(64), 0, stream>>>((const uint32_t*)Wfqv, FLAG);
  prep_w<<<dim3(768), 256, 0, stream>>>(Wfqv, Wfo, WqvP, WfoP, FLAG);
  gemm0_mfma<<<dim3(144, 4), 256, 0, stream>>>(WqvP, feat, FQ, FVt, FLAG);
  map_qv<<<dim3(512, 4), 256, 0, stream>>>(Wmqv, smap, MQ, MVT, FLAG);
  attn_mfma<<<dim3(NGRP, 16), 256, 0, stream>>>(FQ, FVt, MQ, MVT, FQ, P);
  reduce_map<<<dim3(1024), 256, 0, stream>>>(P, MO);
  gemm1_mfma<<<dim3(36, 4, 4), 256, 0, stream>>>(WfoP, FQ, d_out, FLAG);
  map_out_k<<<dim3(256, 4), 256, 0, stream>>>(Wmo, MO, d_out, FLAG);
}